// Round 2
// baseline (702.174 us; speedup 1.0000x reference)
//
#include <hip/hip_runtime.h>
#include <hip/hip_bf16.h>

// Capsule EM routing, fully fused: votes recomputed in registers each pass.
// B=32, H=W=8, I=32 -> N=2048, O=64, P=16, routings=3.
//
// R2: launch-ramp fix. R1 showed 2048 small WGs are launch-rate limited
// (occupancy 30% = block_dur/dispatch_dur, not a capacity limit). Now 512
// WGs x 1024 threads (16 waves): each block owns 4 spatial sites, each
// 4-wave group owns one site, each wave 8 input capsules. 2 blocks/CU x 16
// waves = 32 waves/CU ceiling with only 512 WGs to ramp. Cross-wave reduce
// via LDS atomicAdd (ds_add_f32, lane-contiguous: conflict-free), then one
// coalesced global-atomic flush per block (4x fewer global atomics than R1).

#define NB 32
#define NN 2048
#define NO 64
#define NP 16
#define EPSF 1e-7f

#define SITES_PER_BLK 4
#define NCHUNK 16              // 64 sites / 4 per block
#define BLK_N (SITES_PER_BLK * 32)   // 128 n per block

// accum layout per iteration: [b][slot][o], slots 0..15 = sum rr'*v,
// 16..31 = sum rr'*v^2, 32 = rps.  ACC_PER_B = 33*64 floats.
#define ACC_SLOTS 33
#define ACC_PER_B (ACC_SLOTS * NO)
#define ACC_TOTAL (NB * ACC_PER_B)

// stats layout per iteration: [b][slot][o], slots 0..15 = mean, 16..31 =
// 0.5/var, 32 = zz_base = log(o_act+eps) - sum_p log(sigma+eps)

template <bool FIRST>
__global__ __launch_bounds__(1024, 8) void accum_kernel(
    const float* __restrict__ pose,   // [B][N][16]
    const float* __restrict__ act,    // [B][N]
    const float* __restrict__ wmat,   // [I=32][O=64][16]
    const float* __restrict__ stats,  // [B][33][64] (prev iter) or null
    float* __restrict__ accum)        // [B][33][64] (pre-zeroed)
{
    __shared__ float pose_s[BLK_N * 16];   // 8 KB (4 sites x 32 poses)
    __shared__ float act_s[BLK_N];         // 512 B
    __shared__ float acc_s[ACC_PER_B];     // 8448 B block-level accumulator

    const int b = blockIdx.y;
    const int chunk = blockIdx.x;          // 0..15
    const int n0 = chunk * BLK_N;
    const int tid = threadIdx.x;

    // cooperative load of this chunk's poses + activations; zero LDS accum
    {
        const float4* psrc = (const float4*)(pose + ((size_t)b * NN + n0) * 16);
        float4* pdst = (float4*)pose_s;
        if (tid < BLK_N * 4) pdst[tid] = psrc[tid];   // 512 float4s
        if (tid < BLK_N) act_s[tid] = act[(size_t)b * NN + n0 + tid];
    }
    for (int j = tid; j < ACC_PER_B; j += 1024) acc_s[j] = 0.f;
    __syncthreads();

    const int wv = tid >> 6;    // wave 0..15
    const int grp = wv >> 2;    // site group 0..3 within chunk
    const int wvin = wv & 3;    // i-quarter within site
    const int o = tid & 63;     // lane = output capsule

    float m[16], i2v[16], zzb = 0.f;
    if (!FIRST) {
        const float* st = stats + (size_t)b * ACC_PER_B;
        #pragma unroll
        for (int p = 0; p < 16; p++) m[p] = st[p * 64 + o];
        #pragma unroll
        for (int p = 0; p < 16; p++) i2v[p] = st[(16 + p) * 64 + o];
        zzb = st[32 * 64 + o];
    }

    float accR = 0.f, acc1[16], acc2[16];
    #pragma unroll
    for (int p = 0; p < 16; p++) { acc1[p] = 0.f; acc2[p] = 0.f; }

    const int site = chunk * SITES_PER_BLK + grp;   // 0..63
    const int hh = site >> 3, ww = site & 7;
    const float c0 = (hh + 0.5f) * 0.125f;
    const float c1 = (ww + 0.5f) * 0.125f;

    for (int ii = 0; ii < 8; ii++) {
        const int i = wvin * 8 + ii;     // capsule index 0..31
        const int nl = grp * 32 + i;     // local n within block
        const float4* wp = (const float4*)(wmat + ((size_t)i * 64 + o) * 16);
        float4 w0 = wp[0], w1 = wp[1], w2 = wp[2], w3 = wp[3];  // rows k, cols c
        const float* pr = pose_s + nl * 16;  // broadcast reads (same addr all lanes)
        float v[16];
        #pragma unroll
        for (int a = 0; a < 4; a++) {
            float pa0 = pr[a * 4 + 0], pa1 = pr[a * 4 + 1];
            float pa2 = pr[a * 4 + 2], pa3 = pr[a * 4 + 3];
            v[a * 4 + 0] = pa0 * w0.x + pa1 * w1.x + pa2 * w2.x + pa3 * w3.x;
            v[a * 4 + 1] = pa0 * w0.y + pa1 * w1.y + pa2 * w2.y + pa3 * w3.y;
            v[a * 4 + 2] = pa0 * w0.z + pa1 * w1.z + pa2 * w2.z + pa3 * w3.z;
            v[a * 4 + 3] = pa0 * w0.w + pa1 * w1.w + pa2 * w2.w + pa3 * w3.w;
        }
        v[0] += c0;
        v[1] += c1;

        float rr;
        if (FIRST) {
            rr = 1.0f / 64.0f;
        } else {
            float d = zzb;
            #pragma unroll
            for (int p = 0; p < 16; p++) {
                float t = v[p] - m[p];
                d -= t * t * i2v[p];
            }
            // softmax over the 64 o-lanes (each n owned by exactly one wave)
            float mx = d;
            #pragma unroll
            for (int s = 32; s > 0; s >>= 1) mx = fmaxf(mx, __shfl_xor(mx, s, 64));
            float e = __expf(d - mx);
            float sum = e;
            #pragma unroll
            for (int s = 32; s > 0; s >>= 1) sum += __shfl_xor(sum, s, 64);
            rr = e / sum;
        }
        float rp = rr * act_s[nl];
        accR += rp;
        #pragma unroll
        for (int p = 0; p < 16; p++) {
            acc1[p] += rp * v[p];
            acc2[p] += rp * v[p] * v[p];
        }
    }

    // cross-wave reduce: LDS float atomics (addresses lane-contiguous ->
    // 2 lanes/bank, conflict-free; 16-way same-address pipelined in DS pipe)
    atomicAdd(&acc_s[32 * 64 + o], accR);
    #pragma unroll
    for (int p = 0; p < 16; p++) atomicAdd(&acc_s[p * 64 + o], acc1[p]);
    #pragma unroll
    for (int p = 0; p < 16; p++) atomicAdd(&acc_s[(16 + p) * 64 + o], acc2[p]);
    __syncthreads();

    // coalesced global-atomic flush (one block-level partial per block)
    float* ac = accum + (size_t)b * ACC_PER_B;
    for (int j = tid; j < ACC_PER_B; j += 1024) atomicAdd(ac + j, acc_s[j]);
}

__global__ __launch_bounds__(64) void stats_kernel(
    const float* __restrict__ accum,   // [B][33][64]
    const float* __restrict__ beta_v,  // [64]
    const float* __restrict__ beta_a,  // [64]
    float* __restrict__ stats_out,     // [B][33][64] or null (final)
    float* __restrict__ out,           // null unless final
    float inv_temp)
{
    const int b = blockIdx.x;
    const int o = threadIdx.x;  // 64 threads = 1 wave
    const float* ac = accum + (size_t)b * ACC_PER_B;

    float rps = ac[32 * 64 + o];
    float m[16], var[16];
    float logsum = 0.f;
    #pragma unroll
    for (int p = 0; p < 16; p++) {
        float s1 = ac[p * 64 + o];
        float s2 = ac[(16 + p) * 64 + o];
        float mm = s1 / rps;
        float vv = fmaxf(s2 / rps - mm * mm, 0.f);
        m[p] = mm;
        var[p] = vv;
        logsum += __logf(sqrtf(vv) + EPSF);
    }
    float cost = rps * (16.0f * beta_v[o] + logsum);

    // mean over O
    float cm = cost;
    #pragma unroll
    for (int s = 32; s > 0; s >>= 1) cm += __shfl_xor(cm, s, 64);
    cm *= (1.0f / 64.0f);
    // population stdv over O
    float d = cost - cm;
    float cs = d * d;
    #pragma unroll
    for (int s = 32; s > 0; s >>= 1) cs += __shfl_xor(cs, s, 64);
    cs = sqrtf(cs * (1.0f / 64.0f));

    float x = inv_temp * (beta_a[o] + (cm - cost) / (cs + EPSF));
    float oa = 1.0f / (1.0f + __expf(-x));

    if (stats_out) {
        float* st = stats_out + (size_t)b * ACC_PER_B;
        #pragma unroll
        for (int p = 0; p < 16; p++) st[p * 64 + o] = m[p];
        #pragma unroll
        for (int p = 0; p < 16; p++) st[(16 + p) * 64 + o] = 0.5f / var[p];
        st[32 * 64 + o] = __logf(oa + EPSF) - logsum;
    }
    if (out) {
        float* op = out + ((size_t)b * 64 + o) * 16;
        #pragma unroll
        for (int p = 0; p < 16; p++) op[p] = m[p];
        out[(size_t)NB * NO * NP + (size_t)b * 64 + o] = oa;
    }
}

extern "C" void kernel_launch(void* const* d_in, const int* in_sizes, int n_in,
                              void* d_out, int out_size, void* d_ws, size_t ws_size,
                              hipStream_t stream) {
    const float* pose   = (const float*)d_in[0];  // (32,8,8,32,4,4)
    const float* act    = (const float*)d_in[1];  // (32,8,8,32)
    const float* wmat   = (const float*)d_in[2];  // (32,64,4,4)
    const float* beta_v = (const float*)d_in[3];  // (1,64)
    const float* beta_a = (const float*)d_in[4];  // (1,64)
    float* out = (float*)d_out;
    float* ws = (float*)d_ws;

    float* accum0 = ws;
    float* accum1 = ws + ACC_TOTAL;
    float* accum2 = ws + 2 * (size_t)ACC_TOTAL;
    float* stats0 = ws + 3 * (size_t)ACC_TOTAL;
    float* stats1 = ws + 4 * (size_t)ACC_TOTAL;

    // zero the three accumulator regions (ws is poisoned before every call)
    hipMemsetAsync(ws, 0, 3 * (size_t)ACC_TOTAL * sizeof(float), stream);

    dim3 grid(NCHUNK, NB);
    accum_kernel<true><<<grid, 1024, 0, stream>>>(pose, act, wmat, nullptr, accum0);
    stats_kernel<<<NB, 64, 0, stream>>>(accum0, beta_v, beta_a, stats0, nullptr, 1.0f);
    accum_kernel<false><<<grid, 1024, 0, stream>>>(pose, act, wmat, stats0, accum1);
    stats_kernel<<<NB, 64, 0, stream>>>(accum1, beta_v, beta_a, stats1, nullptr, 2.0f);
    accum_kernel<false><<<grid, 1024, 0, stream>>>(pose, act, wmat, stats1, accum2);
    stats_kernel<<<NB, 64, 0, stream>>>(accum2, beta_v, beta_a, nullptr, out, 3.0f);
}

// Round 3
// 396.753 us; speedup vs baseline: 1.7698x; 1.7698x over previous
//
#include <hip/hip_runtime.h>
#include <hip/hip_bf16.h>

// Capsule EM routing, fully fused: votes recomputed in registers each pass.
// B=32, H=W=8, I=32 -> N=2048, O=64, P=16, routings=3.
//
// R3: fix R2's spill. launch_bounds(1024,8) forced VGPR=32 (hipcc second
// arg behaves like CUDA min-blocks/CU: 8 blocks x 16 waves = 128 waves ->
// cap 32) and the ~96-float working set spilled to scratch (FETCH 435 MB).
// (1024,2) caps at 64 VGPR under CUDA semantics and is unconstraining under
// waves/EU semantics -- either way we get the proven 64-VGPR codegen.
// Structure unchanged from R2: 512 WGs x 1024 threads (16 waves), block owns
// 4 sites, wave owns 8 input capsules; LDS-atomic cross-wave reduce, one
// coalesced global-atomic flush per block.

#define NB 32
#define NN 2048
#define NO 64
#define NP 16
#define EPSF 1e-7f

#define SITES_PER_BLK 4
#define NCHUNK 16              // 64 sites / 4 per block
#define BLK_N (SITES_PER_BLK * 32)   // 128 n per block

// accum layout per iteration: [b][slot][o], slots 0..15 = sum rr'*v,
// 16..31 = sum rr'*v^2, 32 = rps.  ACC_PER_B = 33*64 floats.
#define ACC_SLOTS 33
#define ACC_PER_B (ACC_SLOTS * NO)
#define ACC_TOTAL (NB * ACC_PER_B)

// stats layout per iteration: [b][slot][o], slots 0..15 = mean, 16..31 =
// 0.5/var, 32 = zz_base = log(o_act+eps) - sum_p log(sigma+eps)

template <bool FIRST>
__global__ __launch_bounds__(1024, 2) void accum_kernel(
    const float* __restrict__ pose,   // [B][N][16]
    const float* __restrict__ act,    // [B][N]
    const float* __restrict__ wmat,   // [I=32][O=64][16]
    const float* __restrict__ stats,  // [B][33][64] (prev iter) or null
    float* __restrict__ accum)        // [B][33][64] (pre-zeroed)
{
    __shared__ float pose_s[BLK_N * 16];   // 8 KB (4 sites x 32 poses)
    __shared__ float act_s[BLK_N];         // 512 B
    __shared__ float acc_s[ACC_PER_B];     // 8448 B block-level accumulator

    const int b = blockIdx.y;
    const int chunk = blockIdx.x;          // 0..15
    const int n0 = chunk * BLK_N;
    const int tid = threadIdx.x;

    // cooperative load of this chunk's poses + activations; zero LDS accum
    {
        const float4* psrc = (const float4*)(pose + ((size_t)b * NN + n0) * 16);
        float4* pdst = (float4*)pose_s;
        if (tid < BLK_N * 4) pdst[tid] = psrc[tid];   // 512 float4s
        if (tid < BLK_N) act_s[tid] = act[(size_t)b * NN + n0 + tid];
    }
    for (int j = tid; j < ACC_PER_B; j += 1024) acc_s[j] = 0.f;
    __syncthreads();

    const int wv = tid >> 6;    // wave 0..15
    const int grp = wv >> 2;    // site group 0..3 within chunk
    const int wvin = wv & 3;    // i-quarter within site
    const int o = tid & 63;     // lane = output capsule

    float m[16], i2v[16], zzb = 0.f;
    if (!FIRST) {
        const float* st = stats + (size_t)b * ACC_PER_B;
        #pragma unroll
        for (int p = 0; p < 16; p++) m[p] = st[p * 64 + o];
        #pragma unroll
        for (int p = 0; p < 16; p++) i2v[p] = st[(16 + p) * 64 + o];
        zzb = st[32 * 64 + o];
    }

    float accR = 0.f, acc1[16], acc2[16];
    #pragma unroll
    for (int p = 0; p < 16; p++) { acc1[p] = 0.f; acc2[p] = 0.f; }

    const int site = chunk * SITES_PER_BLK + grp;   // 0..63
    const int hh = site >> 3, ww = site & 7;
    const float c0 = (hh + 0.5f) * 0.125f;
    const float c1 = (ww + 0.5f) * 0.125f;

    for (int ii = 0; ii < 8; ii++) {
        const int i = wvin * 8 + ii;     // capsule index 0..31
        const int nl = grp * 32 + i;     // local n within block
        const float4* wp = (const float4*)(wmat + ((size_t)i * 64 + o) * 16);
        float4 w0 = wp[0], w1 = wp[1], w2 = wp[2], w3 = wp[3];  // rows k, cols c
        const float* pr = pose_s + nl * 16;  // broadcast reads (same addr all lanes)
        float v[16];
        #pragma unroll
        for (int a = 0; a < 4; a++) {
            float pa0 = pr[a * 4 + 0], pa1 = pr[a * 4 + 1];
            float pa2 = pr[a * 4 + 2], pa3 = pr[a * 4 + 3];
            v[a * 4 + 0] = pa0 * w0.x + pa1 * w1.x + pa2 * w2.x + pa3 * w3.x;
            v[a * 4 + 1] = pa0 * w0.y + pa1 * w1.y + pa2 * w2.y + pa3 * w3.y;
            v[a * 4 + 2] = pa0 * w0.z + pa1 * w1.z + pa2 * w2.z + pa3 * w3.z;
            v[a * 4 + 3] = pa0 * w0.w + pa1 * w1.w + pa2 * w2.w + pa3 * w3.w;
        }
        v[0] += c0;
        v[1] += c1;

        float rr;
        if (FIRST) {
            rr = 1.0f / 64.0f;
        } else {
            float d = zzb;
            #pragma unroll
            for (int p = 0; p < 16; p++) {
                float t = v[p] - m[p];
                d -= t * t * i2v[p];
            }
            // softmax over the 64 o-lanes (each n owned by exactly one wave)
            float mx = d;
            #pragma unroll
            for (int s = 32; s > 0; s >>= 1) mx = fmaxf(mx, __shfl_xor(mx, s, 64));
            float e = __expf(d - mx);
            float sum = e;
            #pragma unroll
            for (int s = 32; s > 0; s >>= 1) sum += __shfl_xor(sum, s, 64);
            rr = e / sum;
        }
        float rp = rr * act_s[nl];
        accR += rp;
        #pragma unroll
        for (int p = 0; p < 16; p++) {
            acc1[p] += rp * v[p];
            acc2[p] += rp * v[p] * v[p];
        }
    }

    // cross-wave reduce: LDS float atomics (addresses lane-contiguous ->
    // 2 lanes/bank, conflict-free; same-address adds pipelined in DS pipe)
    atomicAdd(&acc_s[32 * 64 + o], accR);
    #pragma unroll
    for (int p = 0; p < 16; p++) atomicAdd(&acc_s[p * 64 + o], acc1[p]);
    #pragma unroll
    for (int p = 0; p < 16; p++) atomicAdd(&acc_s[(16 + p) * 64 + o], acc2[p]);
    __syncthreads();

    // coalesced global-atomic flush (one block-level partial per block)
    float* ac = accum + (size_t)b * ACC_PER_B;
    for (int j = tid; j < ACC_PER_B; j += 1024) atomicAdd(ac + j, acc_s[j]);
}

__global__ __launch_bounds__(64) void stats_kernel(
    const float* __restrict__ accum,   // [B][33][64]
    const float* __restrict__ beta_v,  // [64]
    const float* __restrict__ beta_a,  // [64]
    float* __restrict__ stats_out,     // [B][33][64] or null (final)
    float* __restrict__ out,           // null unless final
    float inv_temp)
{
    const int b = blockIdx.x;
    const int o = threadIdx.x;  // 64 threads = 1 wave
    const float* ac = accum + (size_t)b * ACC_PER_B;

    float rps = ac[32 * 64 + o];
    float m[16], var[16];
    float logsum = 0.f;
    #pragma unroll
    for (int p = 0; p < 16; p++) {
        float s1 = ac[p * 64 + o];
        float s2 = ac[(16 + p) * 64 + o];
        float mm = s1 / rps;
        float vv = fmaxf(s2 / rps - mm * mm, 0.f);
        m[p] = mm;
        var[p] = vv;
        logsum += __logf(sqrtf(vv) + EPSF);
    }
    float cost = rps * (16.0f * beta_v[o] + logsum);

    // mean over O
    float cm = cost;
    #pragma unroll
    for (int s = 32; s > 0; s >>= 1) cm += __shfl_xor(cm, s, 64);
    cm *= (1.0f / 64.0f);
    // population stdv over O
    float d = cost - cm;
    float cs = d * d;
    #pragma unroll
    for (int s = 32; s > 0; s >>= 1) cs += __shfl_xor(cs, s, 64);
    cs = sqrtf(cs * (1.0f / 64.0f));

    float x = inv_temp * (beta_a[o] + (cm - cost) / (cs + EPSF));
    float oa = 1.0f / (1.0f + __expf(-x));

    if (stats_out) {
        float* st = stats_out + (size_t)b * ACC_PER_B;
        #pragma unroll
        for (int p = 0; p < 16; p++) st[p * 64 + o] = m[p];
        #pragma unroll
        for (int p = 0; p < 16; p++) st[(16 + p) * 64 + o] = 0.5f / var[p];
        st[32 * 64 + o] = __logf(oa + EPSF) - logsum;
    }
    if (out) {
        float* op = out + ((size_t)b * 64 + o) * 16;
        #pragma unroll
        for (int p = 0; p < 16; p++) op[p] = m[p];
        out[(size_t)NB * NO * NP + (size_t)b * 64 + o] = oa;
    }
}

extern "C" void kernel_launch(void* const* d_in, const int* in_sizes, int n_in,
                              void* d_out, int out_size, void* d_ws, size_t ws_size,
                              hipStream_t stream) {
    const float* pose   = (const float*)d_in[0];  // (32,8,8,32,4,4)
    const float* act    = (const float*)d_in[1];  // (32,8,8,32)
    const float* wmat   = (const float*)d_in[2];  // (32,64,4,4)
    const float* beta_v = (const float*)d_in[3];  // (1,64)
    const float* beta_a = (const float*)d_in[4];  // (1,64)
    float* out = (float*)d_out;
    float* ws = (float*)d_ws;

    float* accum0 = ws;
    float* accum1 = ws + ACC_TOTAL;
    float* accum2 = ws + 2 * (size_t)ACC_TOTAL;
    float* stats0 = ws + 3 * (size_t)ACC_TOTAL;
    float* stats1 = ws + 4 * (size_t)ACC_TOTAL;

    // zero the three accumulator regions (ws is poisoned before every call)
    hipMemsetAsync(ws, 0, 3 * (size_t)ACC_TOTAL * sizeof(float), stream);

    dim3 grid(NCHUNK, NB);
    accum_kernel<true><<<grid, 1024, 0, stream>>>(pose, act, wmat, nullptr, accum0);
    stats_kernel<<<NB, 64, 0, stream>>>(accum0, beta_v, beta_a, stats0, nullptr, 1.0f);
    accum_kernel<false><<<grid, 1024, 0, stream>>>(pose, act, wmat, stats0, accum1);
    stats_kernel<<<NB, 64, 0, stream>>>(accum1, beta_v, beta_a, stats1, nullptr, 2.0f);
    accum_kernel<false><<<grid, 1024, 0, stream>>>(pose, act, wmat, stats1, accum2);
    stats_kernel<<<NB, 64, 0, stream>>>(accum2, beta_v, beta_a, nullptr, out, 3.0f);
}

// Round 4
// 212.259 us; speedup vs baseline: 3.3081x; 1.8692x over previous
//
#include <hip/hip_runtime.h>
#include <hip/hip_bf16.h>

// Capsule EM routing, fully fused: votes recomputed in registers each pass.
// B=32, H=W=8, I=32 -> N=2048, O=64, P=16, routings=3.
//
// R4: no atomics anywhere. R3's LDS float atomicAdd lowers to a CAS retry
// loop (safe-fp-atomics default); 16 waves contending on the same 64
// addresses serialized the whole kernel (VALUBusy 14.6%, 116 us). Now:
// wave = one full site (32 i-iters), 512 blocks x 256 thd = 2048 waves.
// Cross-wave combine = R1's proven non-atomic LDS tree (4 waves), then the
// block partial is written with plain coalesced stores to ws; a widened
// stats kernel sums the 16 partials per batch. No global atomics, no LDS
// atomics, no memset. launch_bounds(256,4) caps VGPR at 128 under either
// second-arg semantics (R3 lesson: (1024,8) forced 32 VGPR and spilled).

#define NB 32
#define NN 2048
#define NO 64
#define NP 16
#define EPSF 1e-7f

#define SPB 4                 // sites per block (one per wave)
#define NCHUNK 16             // blocks per batch sample
#define BLK_N (SPB * 32)      // 128 n per block

// partial/stats layout per batch: [slot][o], slots 0..15 = sum rr'*v,
// 16..31 = sum rr'*v^2, 32 = rps (stats: mean / 0.5/var / zz_base).
#define ACC_SLOTS 33
#define ACC_PER_B (ACC_SLOTS * NO)            // 2112 floats
#define PART_TOTAL (NB * NCHUNK * ACC_PER_B)  // 1,081,344 floats

template <bool FIRST>
__global__ __launch_bounds__(256, 4) void accum_kernel(
    const float* __restrict__ pose,   // [B][N][16]
    const float* __restrict__ act,    // [B][N]
    const float* __restrict__ wmat,   // [I=32][O=64][16]
    const float* __restrict__ stats,  // [B][33][64] (prev iter) or null
    float* __restrict__ part)         // [B][16][33*64] block partials
{
    __shared__ float pose_s[BLK_N * 16];     // 8 KB (4 sites x 32 poses)
    __shared__ float act_s[BLK_N];           // 512 B
    __shared__ float red[2][ACC_PER_B];      // 16.9 KB tree-reduce buffer

    const int b = blockIdx.y;
    const int chunk = blockIdx.x;            // 0..15
    const int n0 = chunk * BLK_N;
    const int tid = threadIdx.x;

    // cooperative load of this chunk's poses + activations
    {
        const float4* psrc = (const float4*)(pose + ((size_t)b * NN + n0) * 16);
        float4* pdst = (float4*)pose_s;
        #pragma unroll
        for (int j = tid; j < BLK_N * 4; j += 256) pdst[j] = psrc[j];  // 512 f4
        if (tid < BLK_N) act_s[tid] = act[(size_t)b * NN + n0 + tid];
    }
    __syncthreads();

    const int wv = tid >> 6;    // wave 0..3 -> one site each
    const int o = tid & 63;     // lane = output capsule

    float m[16], i2v[16], zzb = 0.f;
    if (!FIRST) {
        const float* st = stats + (size_t)b * ACC_PER_B;
        #pragma unroll
        for (int p = 0; p < 16; p++) m[p] = st[p * 64 + o];
        #pragma unroll
        for (int p = 0; p < 16; p++) i2v[p] = st[(16 + p) * 64 + o];
        zzb = st[32 * 64 + o];
    }

    float accR = 0.f, acc1[16], acc2[16];
    #pragma unroll
    for (int p = 0; p < 16; p++) { acc1[p] = 0.f; acc2[p] = 0.f; }

    const int site = chunk * SPB + wv;       // 0..63
    const int hh = site >> 3, ww = site & 7;
    const float c0 = (hh + 0.5f) * 0.125f;
    const float c1 = (ww + 0.5f) * 0.125f;

    #pragma unroll 4
    for (int i = 0; i < 32; i++) {
        const int nl = wv * 32 + i;          // local n within block
        const float4* wp = (const float4*)(wmat + ((size_t)i * 64 + o) * 16);
        float4 w0 = wp[0], w1 = wp[1], w2 = wp[2], w3 = wp[3];  // rows k, cols c
        const float* pr = pose_s + nl * 16;  // broadcast reads (same addr all lanes)
        float v[16];
        #pragma unroll
        for (int a = 0; a < 4; a++) {
            float pa0 = pr[a * 4 + 0], pa1 = pr[a * 4 + 1];
            float pa2 = pr[a * 4 + 2], pa3 = pr[a * 4 + 3];
            v[a * 4 + 0] = pa0 * w0.x + pa1 * w1.x + pa2 * w2.x + pa3 * w3.x;
            v[a * 4 + 1] = pa0 * w0.y + pa1 * w1.y + pa2 * w2.y + pa3 * w3.y;
            v[a * 4 + 2] = pa0 * w0.z + pa1 * w1.z + pa2 * w2.z + pa3 * w3.z;
            v[a * 4 + 3] = pa0 * w0.w + pa1 * w1.w + pa2 * w2.w + pa3 * w3.w;
        }
        v[0] += c0;
        v[1] += c1;

        float rr;
        if (FIRST) {
            rr = 1.0f / 64.0f;
        } else {
            float d = zzb;
            #pragma unroll
            for (int p = 0; p < 16; p++) {
                float t = v[p] - m[p];
                d -= t * t * i2v[p];
            }
            // softmax over the 64 o-lanes (this wave owns n entirely)
            float mx = d;
            #pragma unroll
            for (int s = 32; s > 0; s >>= 1) mx = fmaxf(mx, __shfl_xor(mx, s, 64));
            float e = __expf(d - mx);
            float sum = e;
            #pragma unroll
            for (int s = 32; s > 0; s >>= 1) sum += __shfl_xor(sum, s, 64);
            rr = e / sum;
        }
        float rp = rr * act_s[nl];
        accR += rp;
        #pragma unroll
        for (int p = 0; p < 16; p++) {
            acc1[p] += rp * v[p];
            acc2[p] += rp * v[p] * v[p];
        }
    }

    // non-atomic tree reduce across the 4 waves (R1-proven pattern)
    if (wv >= 2) {
        float* r = red[wv - 2];
        r[32 * 64 + o] = accR;
        #pragma unroll
        for (int p = 0; p < 16; p++) r[p * 64 + o] = acc1[p];
        #pragma unroll
        for (int p = 0; p < 16; p++) r[(16 + p) * 64 + o] = acc2[p];
    }
    __syncthreads();
    if (wv < 2) {
        const float* r = red[wv];
        accR += r[32 * 64 + o];
        #pragma unroll
        for (int p = 0; p < 16; p++) acc1[p] += r[p * 64 + o];
        #pragma unroll
        for (int p = 0; p < 16; p++) acc2[p] += r[(16 + p) * 64 + o];
    }
    __syncthreads();
    if (wv == 1) {
        float* r = red[0];
        r[32 * 64 + o] = accR;
        #pragma unroll
        for (int p = 0; p < 16; p++) r[p * 64 + o] = acc1[p];
        #pragma unroll
        for (int p = 0; p < 16; p++) r[(16 + p) * 64 + o] = acc2[p];
    }
    __syncthreads();
    if (wv == 0) {
        const float* r = red[0];
        accR += r[32 * 64 + o];
        #pragma unroll
        for (int p = 0; p < 16; p++) acc1[p] += r[p * 64 + o];
        #pragma unroll
        for (int p = 0; p < 16; p++) acc2[p] += r[(16 + p) * 64 + o];

        // plain coalesced stores of the block partial (no atomics)
        float* pc = part + ((size_t)b * NCHUNK + chunk) * ACC_PER_B;
        pc[32 * 64 + o] = accR;
        #pragma unroll
        for (int p = 0; p < 16; p++) pc[p * 64 + o] = acc1[p];
        #pragma unroll
        for (int p = 0; p < 16; p++) pc[(16 + p) * 64 + o] = acc2[p];
    }
}

__global__ __launch_bounds__(256) void stats_kernel(
    const float* __restrict__ part,    // [B][16][33*64]
    const float* __restrict__ beta_v,  // [64]
    const float* __restrict__ beta_a,  // [64]
    float* __restrict__ stats_out,     // [B][33][64] or null (final)
    float* __restrict__ out,           // null unless final
    float inv_temp)
{
    __shared__ float acc_s[ACC_PER_B];

    const int b = blockIdx.x;
    const int tid = threadIdx.x;

    // sum the 16 block partials (vectorized, L2-resident)
    {
        const float4* p4 = (const float4*)(part + (size_t)b * NCHUNK * ACC_PER_B);
        float4* a4 = (float4*)acc_s;
        for (int j = tid; j < ACC_PER_B / 4; j += 256) {
            float4 s = make_float4(0.f, 0.f, 0.f, 0.f);
            #pragma unroll
            for (int c = 0; c < NCHUNK; c++) {
                float4 v = p4[c * (ACC_PER_B / 4) + j];
                s.x += v.x; s.y += v.y; s.z += v.z; s.w += v.w;
            }
            a4[j] = s;
        }
    }
    __syncthreads();

    if (tid < 64) {
        const int o = tid;
        float rps = acc_s[32 * 64 + o];
        float m[16], var[16];
        float logsum = 0.f;
        #pragma unroll
        for (int p = 0; p < 16; p++) {
            float s1 = acc_s[p * 64 + o];
            float s2 = acc_s[(16 + p) * 64 + o];
            float mm = s1 / rps;
            float vv = fmaxf(s2 / rps - mm * mm, 0.f);
            m[p] = mm;
            var[p] = vv;
            logsum += __logf(sqrtf(vv) + EPSF);
        }
        float cost = rps * (16.0f * beta_v[o] + logsum);

        // mean over O
        float cm = cost;
        #pragma unroll
        for (int s = 32; s > 0; s >>= 1) cm += __shfl_xor(cm, s, 64);
        cm *= (1.0f / 64.0f);
        // population stdv over O
        float d = cost - cm;
        float cs = d * d;
        #pragma unroll
        for (int s = 32; s > 0; s >>= 1) cs += __shfl_xor(cs, s, 64);
        cs = sqrtf(cs * (1.0f / 64.0f));

        float x = inv_temp * (beta_a[o] + (cm - cost) / (cs + EPSF));
        float oa = 1.0f / (1.0f + __expf(-x));

        if (stats_out) {
            float* st = stats_out + (size_t)b * ACC_PER_B;
            #pragma unroll
            for (int p = 0; p < 16; p++) st[p * 64 + o] = m[p];
            #pragma unroll
            for (int p = 0; p < 16; p++) st[(16 + p) * 64 + o] = 0.5f / var[p];
            st[32 * 64 + o] = __logf(oa + EPSF) - logsum;
        }
        if (out) {
            float* op = out + ((size_t)b * 64 + o) * 16;
            #pragma unroll
            for (int p = 0; p < 16; p++) op[p] = m[p];
            out[(size_t)NB * NO * NP + (size_t)b * 64 + o] = oa;
        }
    }
}

extern "C" void kernel_launch(void* const* d_in, const int* in_sizes, int n_in,
                              void* d_out, int out_size, void* d_ws, size_t ws_size,
                              hipStream_t stream) {
    const float* pose   = (const float*)d_in[0];  // (32,8,8,32,4,4)
    const float* act    = (const float*)d_in[1];  // (32,8,8,32)
    const float* wmat   = (const float*)d_in[2];  // (32,64,4,4)
    const float* beta_v = (const float*)d_in[3];  // (1,64)
    const float* beta_a = (const float*)d_in[4];  // (1,64)
    float* out = (float*)d_out;
    float* ws = (float*)d_ws;

    float* part   = ws;                              // 1,081,344 floats
    float* stats0 = ws + (size_t)PART_TOTAL;         //    67,584 floats
    float* stats1 = stats0 + (size_t)NB * ACC_PER_B; //    67,584 floats
    // total 4.87 MB; every read slot is written unconditionally -> no memset

    dim3 grid(NCHUNK, NB);
    accum_kernel<true><<<grid, 256, 0, stream>>>(pose, act, wmat, nullptr, part);
    stats_kernel<<<NB, 256, 0, stream>>>(part, beta_v, beta_a, stats0, nullptr, 1.0f);
    accum_kernel<false><<<grid, 256, 0, stream>>>(pose, act, wmat, stats0, part);
    stats_kernel<<<NB, 256, 0, stream>>>(part, beta_v, beta_a, stats1, nullptr, 2.0f);
    accum_kernel<false><<<grid, 256, 0, stream>>>(pose, act, wmat, stats1, part);
    stats_kernel<<<NB, 256, 0, stream>>>(part, beta_v, beta_a, nullptr, out, 3.0f);
}

// Round 5
// 171.356 us; speedup vs baseline: 4.0977x; 1.2387x over previous
//
#include <hip/hip_runtime.h>
#include <hip/hip_bf16.h>

// Capsule EM routing, fully fused: votes recomputed in registers each pass.
// B=32, H=W=8, I=32 -> N=2048, O=64, P=16, routings=3.
//
// R5: fat blocks done right. Established: per-pass VALU floor ~16us needs
// ~32 waves/CU; 2048-WG grids ramp at ~70 WG/us (30us!) so blocks must be
// fat; R2 failed via launch_bounds-forced spill, R3 via LDS fp32 atomicAdd
// (CAS retry storm), R4 via `#pragma unroll 4` spill (FETCH 15.9MB, WRITE
// 43.5MB). This round: 512 WGs x 1024 thd (16 waves), 4 groups x 4 waves,
// group = one site, wave = 8 i-iters (R1's proven body, no pragmas, plain
// launch_bounds -> natural 64-VGPR codegen). Cross-wave reduce is
// NON-ATOMIC: 3 barrier-sequenced in-place add rounds into one 8.4KB LDS
// buffer per group, then a coalesced 4-buffer sum + plain global stores.
// LDS 42.5KB/block -> 2 blocks/CU = 32 waves/CU. No atomics, no memset.

#define NB 32
#define NN 2048
#define NO 64
#define NP 16
#define EPSF 1e-7f

#define SPB 4                 // sites per block (one per 4-wave group)
#define NCHUNK 16             // blocks per batch sample
#define BLK_N (SPB * 32)      // 128 n per block

// partial/stats layout per batch: [slot][o], slots 0..15 = sum rr'*v,
// 16..31 = sum rr'*v^2, 32 = rps (stats: mean / 0.5/var / zz_base).
#define ACC_SLOTS 33
#define ACC_PER_B (ACC_SLOTS * NO)            // 2112 floats
#define PART_TOTAL (NB * NCHUNK * ACC_PER_B)  // 1,081,344 floats

template <bool FIRST>
__global__ __launch_bounds__(1024) void accum_kernel(
    const float* __restrict__ pose,   // [B][N][16]
    const float* __restrict__ act,    // [B][N]
    const float* __restrict__ wmat,   // [I=32][O=64][16]
    const float* __restrict__ stats,  // [B][33][64] (prev iter) or null
    float* __restrict__ part)         // [B][16][33*64] block partials
{
    __shared__ float pose_s[BLK_N * 16];     // 8 KB (4 sites x 32 poses)
    __shared__ float act_s[BLK_N];           // 512 B
    __shared__ float buf[SPB][ACC_PER_B];    // 33.8 KB group partials

    const int b = blockIdx.y;
    const int chunk = blockIdx.x;            // 0..15
    const int n0 = chunk * BLK_N;
    const int tid = threadIdx.x;

    // cooperative load of this chunk's poses + activations
    {
        const float4* psrc = (const float4*)(pose + ((size_t)b * NN + n0) * 16);
        float4* pdst = (float4*)pose_s;
        if (tid < BLK_N * 4) pdst[tid] = psrc[tid];   // 512 float4s
        if (tid < BLK_N) act_s[tid] = act[(size_t)b * NN + n0 + tid];
    }
    __syncthreads();

    const int wv = tid >> 6;    // wave 0..15
    const int grp = wv >> 2;    // site group 0..3 within chunk
    const int wvin = wv & 3;    // i-quarter within site
    const int o = tid & 63;     // lane = output capsule

    float m[16], i2v[16], zzb = 0.f;
    if (!FIRST) {
        const float* st = stats + (size_t)b * ACC_PER_B;
        #pragma unroll
        for (int p = 0; p < 16; p++) m[p] = st[p * 64 + o];
        #pragma unroll
        for (int p = 0; p < 16; p++) i2v[p] = st[(16 + p) * 64 + o];
        zzb = st[32 * 64 + o];
    }

    float accR = 0.f, acc1[16], acc2[16];
    #pragma unroll
    for (int p = 0; p < 16; p++) { acc1[p] = 0.f; acc2[p] = 0.f; }

    const int site = chunk * SPB + grp;      // 0..63
    const int hh = site >> 3, ww = site & 7;
    const float c0 = (hh + 0.5f) * 0.125f;
    const float c1 = (ww + 0.5f) * 0.125f;

    for (int ii = 0; ii < 8; ii++) {
        const int i = wvin * 8 + ii;         // capsule index 0..31
        const int nl = grp * 32 + i;         // local n within block
        const float4* wp = (const float4*)(wmat + ((size_t)i * 64 + o) * 16);
        float4 w0 = wp[0], w1 = wp[1], w2 = wp[2], w3 = wp[3];  // rows k, cols c
        const float* pr = pose_s + nl * 16;  // broadcast reads (same addr all lanes)
        float v[16];
        #pragma unroll
        for (int a = 0; a < 4; a++) {
            float pa0 = pr[a * 4 + 0], pa1 = pr[a * 4 + 1];
            float pa2 = pr[a * 4 + 2], pa3 = pr[a * 4 + 3];
            v[a * 4 + 0] = pa0 * w0.x + pa1 * w1.x + pa2 * w2.x + pa3 * w3.x;
            v[a * 4 + 1] = pa0 * w0.y + pa1 * w1.y + pa2 * w2.y + pa3 * w3.y;
            v[a * 4 + 2] = pa0 * w0.z + pa1 * w1.z + pa2 * w2.z + pa3 * w3.z;
            v[a * 4 + 3] = pa0 * w0.w + pa1 * w1.w + pa2 * w2.w + pa3 * w3.w;
        }
        v[0] += c0;
        v[1] += c1;

        float rr;
        if (FIRST) {
            rr = 1.0f / 64.0f;
        } else {
            float d = zzb;
            #pragma unroll
            for (int p = 0; p < 16; p++) {
                float t = v[p] - m[p];
                d -= t * t * i2v[p];
            }
            // softmax over the 64 o-lanes (each n owned by exactly one wave)
            float mx = d;
            #pragma unroll
            for (int s = 32; s > 0; s >>= 1) mx = fmaxf(mx, __shfl_xor(mx, s, 64));
            float e = __expf(d - mx);
            float sum = e;
            #pragma unroll
            for (int s = 32; s > 0; s >>= 1) sum += __shfl_xor(sum, s, 64);
            rr = e / sum;
        }
        float rp = rr * act_s[nl];
        accR += rp;
        #pragma unroll
        for (int p = 0; p < 16; p++) {
            acc1[p] += rp * v[p];
            acc2[p] += rp * v[p] * v[p];
        }
    }

    // non-atomic cross-wave reduce: 3 barrier-sequenced rounds of in-place
    // adds into buf[grp] (addresses s*64+o -> 2 lanes/bank, conflict-free)
    if (wvin == 3) {
        float* r = buf[grp];
        r[32 * 64 + o] = accR;
        #pragma unroll
        for (int p = 0; p < 16; p++) r[p * 64 + o] = acc1[p];
        #pragma unroll
        for (int p = 0; p < 16; p++) r[(16 + p) * 64 + o] = acc2[p];
    }
    __syncthreads();
    if (wvin == 2) {
        float* r = buf[grp];
        r[32 * 64 + o] += accR;
        #pragma unroll
        for (int p = 0; p < 16; p++) r[p * 64 + o] += acc1[p];
        #pragma unroll
        for (int p = 0; p < 16; p++) r[(16 + p) * 64 + o] += acc2[p];
    }
    __syncthreads();
    if (wvin == 1) {
        float* r = buf[grp];
        r[32 * 64 + o] += accR;
        #pragma unroll
        for (int p = 0; p < 16; p++) r[p * 64 + o] += acc1[p];
        #pragma unroll
        for (int p = 0; p < 16; p++) r[(16 + p) * 64 + o] += acc2[p];
    }
    __syncthreads();
    if (wvin == 0) {
        float* r = buf[grp];
        r[32 * 64 + o] += accR;
        #pragma unroll
        for (int p = 0; p < 16; p++) r[p * 64 + o] += acc1[p];
        #pragma unroll
        for (int p = 0; p < 16; p++) r[(16 + p) * 64 + o] += acc2[p];
    }
    __syncthreads();

    // block partial = sum of the 4 group buffers; plain coalesced stores
    float* pc = part + ((size_t)b * NCHUNK + chunk) * ACC_PER_B;
    for (int j = tid; j < ACC_PER_B; j += 1024)
        pc[j] = buf[0][j] + buf[1][j] + buf[2][j] + buf[3][j];
}

__global__ __launch_bounds__(256) void stats_kernel(
    const float* __restrict__ part,    // [B][16][33*64]
    const float* __restrict__ beta_v,  // [64]
    const float* __restrict__ beta_a,  // [64]
    float* __restrict__ stats_out,     // [B][33][64] or null (final)
    float* __restrict__ out,           // null unless final
    float inv_temp)
{
    __shared__ float acc_s[ACC_PER_B];

    const int b = blockIdx.x;
    const int tid = threadIdx.x;

    // sum the 16 block partials (vectorized, L2-resident)
    {
        const float4* p4 = (const float4*)(part + (size_t)b * NCHUNK * ACC_PER_B);
        float4* a4 = (float4*)acc_s;
        for (int j = tid; j < ACC_PER_B / 4; j += 256) {
            float4 s = make_float4(0.f, 0.f, 0.f, 0.f);
            #pragma unroll
            for (int c = 0; c < NCHUNK; c++) {
                float4 v = p4[c * (ACC_PER_B / 4) + j];
                s.x += v.x; s.y += v.y; s.z += v.z; s.w += v.w;
            }
            a4[j] = s;
        }
    }
    __syncthreads();

    if (tid < 64) {
        const int o = tid;
        float rps = acc_s[32 * 64 + o];
        float m[16], var[16];
        float logsum = 0.f;
        #pragma unroll
        for (int p = 0; p < 16; p++) {
            float s1 = acc_s[p * 64 + o];
            float s2 = acc_s[(16 + p) * 64 + o];
            float mm = s1 / rps;
            float vv = fmaxf(s2 / rps - mm * mm, 0.f);
            m[p] = mm;
            var[p] = vv;
            logsum += __logf(sqrtf(vv) + EPSF);
        }
        float cost = rps * (16.0f * beta_v[o] + logsum);

        // mean over O
        float cm = cost;
        #pragma unroll
        for (int s = 32; s > 0; s >>= 1) cm += __shfl_xor(cm, s, 64);
        cm *= (1.0f / 64.0f);
        // population stdv over O
        float d = cost - cm;
        float cs = d * d;
        #pragma unroll
        for (int s = 32; s > 0; s >>= 1) cs += __shfl_xor(cs, s, 64);
        cs = sqrtf(cs * (1.0f / 64.0f));

        float x = inv_temp * (beta_a[o] + (cm - cost) / (cs + EPSF));
        float oa = 1.0f / (1.0f + __expf(-x));

        if (stats_out) {
            float* st = stats_out + (size_t)b * ACC_PER_B;
            #pragma unroll
            for (int p = 0; p < 16; p++) st[p * 64 + o] = m[p];
            #pragma unroll
            for (int p = 0; p < 16; p++) st[(16 + p) * 64 + o] = 0.5f / var[p];
            st[32 * 64 + o] = __logf(oa + EPSF) - logsum;
        }
        if (out) {
            float* op = out + ((size_t)b * 64 + o) * 16;
            #pragma unroll
            for (int p = 0; p < 16; p++) op[p] = m[p];
            out[(size_t)NB * NO * NP + (size_t)b * 64 + o] = oa;
        }
    }
}

extern "C" void kernel_launch(void* const* d_in, const int* in_sizes, int n_in,
                              void* d_out, int out_size, void* d_ws, size_t ws_size,
                              hipStream_t stream) {
    const float* pose   = (const float*)d_in[0];  // (32,8,8,32,4,4)
    const float* act    = (const float*)d_in[1];  // (32,8,8,32)
    const float* wmat   = (const float*)d_in[2];  // (32,64,4,4)
    const float* beta_v = (const float*)d_in[3];  // (1,64)
    const float* beta_a = (const float*)d_in[4];  // (1,64)
    float* out = (float*)d_out;
    float* ws = (float*)d_ws;

    float* part   = ws;                              // 1,081,344 floats
    float* stats0 = ws + (size_t)PART_TOTAL;         //    67,584 floats
    float* stats1 = stats0 + (size_t)NB * ACC_PER_B; //    67,584 floats
    // total 4.87 MB; every read slot is written unconditionally -> no memset

    dim3 grid(NCHUNK, NB);
    accum_kernel<true><<<grid, 1024, 0, stream>>>(pose, act, wmat, nullptr, part);
    stats_kernel<<<NB, 256, 0, stream>>>(part, beta_v, beta_a, stats0, nullptr, 1.0f);
    accum_kernel<false><<<grid, 1024, 0, stream>>>(pose, act, wmat, stats0, part);
    stats_kernel<<<NB, 256, 0, stream>>>(part, beta_v, beta_a, stats1, nullptr, 2.0f);
    accum_kernel<false><<<grid, 1024, 0, stream>>>(pose, act, wmat, stats1, part);
    stats_kernel<<<NB, 256, 0, stream>>>(part, beta_v, beta_a, nullptr, out, 3.0f);
}

// Round 7
// 170.820 us; speedup vs baseline: 4.1106x; 1.0031x over previous
//
#include <hip/hip_runtime.h>

// Capsule EM routing, fully fused: votes recomputed in registers each pass.
// B=32, H=W=8, I=32 -> N=2048, O=64, P=16, routings=3.
//
// R7: DS-pipe offload + launch fusion (no cooperative launch -- R6's
// hipLaunchCooperativeKernel poisoned graph capture and crashed the run).
// Established: accum is stuck at ~40-50us/pass independent of occupancy
// (8 vs 32 waves/CU) -> shared-resource bound, and the DS pipe is the
// largest consumer (~16 scalar ds_read pose broadcasts + ~13 shuffle ops
// per iter ~= 15us/CU/pass vs VALU ~11us). Pose/act reads are wave-uniform
// -> move them to the idle SMEM pipe via readfirstlane-forced scalar loads;
// LDS pose staging deleted. Stats fused into the following accum kernel
// (each block redundantly computes its batch's stats from the previous
// pass's partials; part is double-buffered to avoid the cross-block RAW
// race). 6 launches -> 4. All other primitives are the R5-proven ones:
// fat 16-wave blocks, 512 WGs, non-atomic barrier-sequenced LDS reduce,
// plain launch_bounds(1024), no unroll pragmas, no atomics, no memset.

#define NB 32
#define NN 2048
#define NO 64
#define NP 16
#define EPSF 1e-7f

#define SPB 4                 // sites per block (one per 4-wave group)
#define NCHUNK 16             // chunks per batch sample
#define BLK_N (SPB * 32)      // 128 n per block

// partial/stats layout per batch: [slot][o], slots 0..15 = sum rr'*v,
// 16..31 = sum rr'*v^2, 32 = rps (stats form: mean / 0.5/var / zz_base).
#define ACC_SLOTS 33
#define ACC_PER_B (ACC_SLOTS * NO)              // 2112 floats
#define PART_PER_BATCH (NCHUNK * ACC_PER_B)     // 33792 floats
#define PART_TOTAL (NB * PART_PER_BATCH)        // 1,081,344 floats

// non-atomic cross-wave reduce (barrier-sequenced) + coalesced partial store
__device__ __forceinline__ void reduce_store(
    float buf[SPB][ACC_PER_B], int wvin, int grp, int o, int tid,
    float accR, const float* acc1, const float* acc2, float* __restrict__ pc)
{
    if (wvin == 3) {
        float* r = buf[grp];
        r[32 * 64 + o] = accR;
        #pragma unroll
        for (int p = 0; p < 16; p++) r[p * 64 + o] = acc1[p];
        #pragma unroll
        for (int p = 0; p < 16; p++) r[(16 + p) * 64 + o] = acc2[p];
    }
    __syncthreads();
    for (int round = 2; round >= 0; --round) {
        if (wvin == round) {
            float* r = buf[grp];
            r[32 * 64 + o] += accR;
            #pragma unroll
            for (int p = 0; p < 16; p++) r[p * 64 + o] += acc1[p];
            #pragma unroll
            for (int p = 0; p < 16; p++) r[(16 + p) * 64 + o] += acc2[p];
        }
        __syncthreads();
    }
    for (int j = tid; j < ACC_PER_B; j += 1024)
        pc[j] = buf[0][j] + buf[1][j] + buf[2][j] + buf[3][j];
}

template <bool FIRST>
__global__ __launch_bounds__(1024) void accum_kernel(
    const float* __restrict__ pose,      // [B][N][16]
    const float* __restrict__ act,       // [B][N]
    const float* __restrict__ wmat,      // [I=32][O=64][16]
    const float* __restrict__ beta_v,    // [64]
    const float* __restrict__ beta_a,    // [64]
    const float* __restrict__ part_prev, // [B][16][33*64] or null (FIRST)
    float* __restrict__ part_out,        // [B][16][33*64]
    float inv_temp)                      // for the inline stats (prev iter)
{
    __shared__ float buf[SPB][ACC_PER_B];    // 33.8 KB

    const int b = blockIdx.y;
    const int chunk = blockIdx.x;            // 0..15
    const int n0 = chunk * BLK_N;
    const int tid = threadIdx.x;
    const int wv = tid >> 6, grp = wv >> 2, wvin = wv & 3, o = tid & 63;

    float m[16], i2v[16], zzb = 0.f;
    if (!FIRST) {
        // ---- inline stats of the previous pass (redundant per block) ----
        float* sb = buf[0];
        {
            const float4* p4 = (const float4*)(part_prev + (size_t)b * PART_PER_BATCH);
            float4* a4 = (float4*)sb;
            for (int j = tid; j < ACC_PER_B / 4; j += 1024) {
                float4 s = make_float4(0.f, 0.f, 0.f, 0.f);
                #pragma unroll
                for (int c = 0; c < NCHUNK; c++) {
                    float4 vv = p4[c * (ACC_PER_B / 4) + j];
                    s.x += vv.x; s.y += vv.y; s.z += vv.z; s.w += vv.w;
                }
                a4[j] = s;
            }
        }
        __syncthreads();
        if (tid < 64) {   // one wave does the per-o stats math, in place
            float rps = sb[32 * 64 + o];
            float mm[16], var[16];
            float logsum = 0.f;
            #pragma unroll
            for (int p = 0; p < 16; p++) {
                float s1 = sb[p * 64 + o];
                float s2 = sb[(16 + p) * 64 + o];
                float mv = s1 / rps;
                float vv = fmaxf(s2 / rps - mv * mv, 0.f);
                mm[p] = mv;
                var[p] = vv;
                logsum += __logf(sqrtf(vv) + EPSF);
            }
            float cost = rps * (16.0f * beta_v[o] + logsum);
            float cm = cost;
            #pragma unroll
            for (int s = 32; s > 0; s >>= 1) cm += __shfl_xor(cm, s, 64);
            cm *= (1.0f / 64.0f);
            float dd = cost - cm;
            float cs = dd * dd;
            #pragma unroll
            for (int s = 32; s > 0; s >>= 1) cs += __shfl_xor(cs, s, 64);
            cs = sqrtf(cs * (1.0f / 64.0f));
            float x = inv_temp * (beta_a[o] + (cm - cost) / (cs + EPSF));
            float oa = 1.0f / (1.0f + __expf(-x));
            #pragma unroll
            for (int p = 0; p < 16; p++) sb[p * 64 + o] = mm[p];
            #pragma unroll
            for (int p = 0; p < 16; p++) sb[(16 + p) * 64 + o] = 0.5f / var[p];
            sb[32 * 64 + o] = __logf(oa + EPSF) - logsum;
        }
        __syncthreads();
        #pragma unroll
        for (int p = 0; p < 16; p++) m[p] = sb[p * 64 + o];
        #pragma unroll
        for (int p = 0; p < 16; p++) i2v[p] = sb[(16 + p) * 64 + o];
        zzb = sb[32 * 64 + o];
        __syncthreads();   // everyone done reading before buf reuse in reduce
    }

    // ---- accumulation pass (pose/act via wave-uniform SCALAR loads) ----
    const float* pose_b = pose + ((size_t)b * NN + n0) * 16;
    const float* act_b  = act + (size_t)b * NN + n0;
    const int site = chunk * SPB + grp;      // 0..63
    const float c0 = ((site >> 3) + 0.5f) * 0.125f;
    const float c1 = ((site & 7) + 0.5f) * 0.125f;

    float accR = 0.f, acc1[16], acc2[16];
    #pragma unroll
    for (int p = 0; p < 16; p++) { acc1[p] = 0.f; acc2[p] = 0.f; }

    for (int ii = 0; ii < 8; ii++) {
        const int i = wvin * 8 + ii;         // capsule index 0..31
        // wave-uniform local n -> scalar (SMEM-pipe) pose/act loads
        const int nl = __builtin_amdgcn_readfirstlane(grp * 32 + i);
        const float4* pr4 = (const float4*)(pose_b + (size_t)nl * 16);
        const float av = act_b[nl];

        const float4* wp = (const float4*)(wmat + ((size_t)i * 64 + o) * 16);
        float4 w0 = wp[0], w1 = wp[1], w2 = wp[2], w3 = wp[3];  // rows k

        float v[16];
        #pragma unroll
        for (int a = 0; a < 4; a++) {
            float4 pa = pr4[a];
            v[a * 4 + 0] = pa.x * w0.x + pa.y * w1.x + pa.z * w2.x + pa.w * w3.x;
            v[a * 4 + 1] = pa.x * w0.y + pa.y * w1.y + pa.z * w2.y + pa.w * w3.y;
            v[a * 4 + 2] = pa.x * w0.z + pa.y * w1.z + pa.z * w2.z + pa.w * w3.z;
            v[a * 4 + 3] = pa.x * w0.w + pa.y * w1.w + pa.z * w2.w + pa.w * w3.w;
        }
        v[0] += c0;
        v[1] += c1;

        float rr;
        if (FIRST) {
            rr = 1.0f / 64.0f;
        } else {
            float d = zzb;
            #pragma unroll
            for (int p = 0; p < 16; p++) {
                float t = v[p] - m[p];
                d -= t * t * i2v[p];
            }
            // softmax over the 64 o-lanes
            float mx = d;
            #pragma unroll
            for (int s = 32; s > 0; s >>= 1) mx = fmaxf(mx, __shfl_xor(mx, s, 64));
            float e = __expf(d - mx);
            float sum = e;
            #pragma unroll
            for (int s = 32; s > 0; s >>= 1) sum += __shfl_xor(sum, s, 64);
            rr = e / sum;
        }
        float rp = rr * av;
        accR += rp;
        #pragma unroll
        for (int p = 0; p < 16; p++) {
            acc1[p] += rp * v[p];
            acc2[p] += rp * v[p] * v[p];
        }
    }

    float* pc = part_out + ((size_t)b * NCHUNK + chunk) * ACC_PER_B;
    reduce_store(buf, wvin, grp, o, tid, accR, acc1, acc2, pc);
}

__global__ __launch_bounds__(256) void stats_final(
    const float* __restrict__ part,    // [B][16][33*64]
    const float* __restrict__ beta_v,  // [64]
    const float* __restrict__ beta_a,  // [64]
    float* __restrict__ out,
    float inv_temp)
{
    __shared__ float acc_s[ACC_PER_B];

    const int b = blockIdx.x;
    const int tid = threadIdx.x;

    {
        const float4* p4 = (const float4*)(part + (size_t)b * PART_PER_BATCH);
        float4* a4 = (float4*)acc_s;
        for (int j = tid; j < ACC_PER_B / 4; j += 256) {
            float4 s = make_float4(0.f, 0.f, 0.f, 0.f);
            #pragma unroll
            for (int c = 0; c < NCHUNK; c++) {
                float4 vv = p4[c * (ACC_PER_B / 4) + j];
                s.x += vv.x; s.y += vv.y; s.z += vv.z; s.w += vv.w;
            }
            a4[j] = s;
        }
    }
    __syncthreads();

    if (tid < 64) {
        const int o = tid;
        float rps = acc_s[32 * 64 + o];
        float m[16];
        float logsum = 0.f;
        #pragma unroll
        for (int p = 0; p < 16; p++) {
            float s1 = acc_s[p * 64 + o];
            float s2 = acc_s[(16 + p) * 64 + o];
            float mm = s1 / rps;
            float vv = fmaxf(s2 / rps - mm * mm, 0.f);
            m[p] = mm;
            logsum += __logf(sqrtf(vv) + EPSF);
        }
        float cost = rps * (16.0f * beta_v[o] + logsum);

        float cm = cost;
        #pragma unroll
        for (int s = 32; s > 0; s >>= 1) cm += __shfl_xor(cm, s, 64);
        cm *= (1.0f / 64.0f);
        float dd = cost - cm;
        float cs = dd * dd;
        #pragma unroll
        for (int s = 32; s > 0; s >>= 1) cs += __shfl_xor(cs, s, 64);
        cs = sqrtf(cs * (1.0f / 64.0f));

        float x = inv_temp * (beta_a[o] + (cm - cost) / (cs + EPSF));
        float oa = 1.0f / (1.0f + __expf(-x));

        float* op = out + ((size_t)b * 64 + o) * 16;
        #pragma unroll
        for (int p = 0; p < 16; p++) op[p] = m[p];
        out[(size_t)NB * NO * NP + (size_t)b * 64 + o] = oa;
    }
}

extern "C" void kernel_launch(void* const* d_in, const int* in_sizes, int n_in,
                              void* d_out, int out_size, void* d_ws, size_t ws_size,
                              hipStream_t stream) {
    const float* pose   = (const float*)d_in[0];  // (32,8,8,32,4,4)
    const float* act    = (const float*)d_in[1];  // (32,8,8,32)
    const float* wmat   = (const float*)d_in[2];  // (32,64,4,4)
    const float* beta_v = (const float*)d_in[3];  // (1,64)
    const float* beta_a = (const float*)d_in[4];  // (1,64)
    float* out = (float*)d_out;
    float* ws = (float*)d_ws;

    float* pA = ws;                        // 1,081,344 floats
    float* pB = ws + (size_t)PART_TOTAL;   // 1,081,344 floats (double buffer)
    // every read slot is written by the preceding launch -> no memset

    dim3 grid(NCHUNK, NB);
    accum_kernel<true ><<<grid, 1024, 0, stream>>>(pose, act, wmat, beta_v, beta_a,
                                                   nullptr, pA, 0.0f);
    accum_kernel<false><<<grid, 1024, 0, stream>>>(pose, act, wmat, beta_v, beta_a,
                                                   pA, pB, 1.0f);
    accum_kernel<false><<<grid, 1024, 0, stream>>>(pose, act, wmat, beta_v, beta_a,
                                                   pB, pA, 2.0f);
    stats_final<<<NB, 256, 0, stream>>>(pA, beta_v, beta_a, out, 3.0f);
}